// Round 1
// baseline (886.261 us; speedup 1.0000x reference)
//
#include <hip/hip_runtime.h>
#include <hip/hip_bf16.h>

typedef __bf16 bf16;
typedef __attribute__((ext_vector_type(8))) bf16 bf16x8;
typedef __attribute__((ext_vector_type(4))) float f32x4;

constexpr int B_   = 16;
constexpr int E_   = 400;
constexpr int R_   = 624;
constexpr int N_   = 1024;
constexpr int HSZ_ = 512;
constexpr int DFF_ = 2048;
constexpr int M_   = B_ * N_;

// global -> LDS direct DMA, 16B per lane. LDS dest must be wave-uniform base
// + lane*16 (guide §5); our e = i*256 + w*64 + lane mapping satisfies this.
__device__ __forceinline__ void glds16(const void* g, void* l) {
    __builtin_amdgcn_global_load_lds((const __attribute__((address_space(1))) void*)g,
                                     (__attribute__((address_space(3))) void*)l,
                                     16, 0, 0);
}

// ---------------------------------------------------------------------------
__global__ __launch_bounds__(256) void transpose_f32_bf16(const float* __restrict__ in,
                                                          bf16* __restrict__ out,
                                                          int rows, int cols) {
    __shared__ float tile[32][33];
    int c0 = blockIdx.x * 32, r0 = blockIdx.y * 32;
    int tx = threadIdx.x, ty = threadIdx.y;   // 32 x 8
    #pragma unroll
    for (int i = 0; i < 32; i += 8)
        tile[ty + i][tx] = in[(size_t)(r0 + ty + i) * cols + (c0 + tx)];
    __syncthreads();
    #pragma unroll
    for (int i = 0; i < 32; i += 8)
        out[(size_t)(c0 + ty + i) * rows + (r0 + tx)] = (bf16)tile[tx][ty + i];
}

// ---------------------------------------------------------------------------
__global__ __launch_bounds__(256) void pack_adj(const int* __restrict__ adj,
                                                unsigned* __restrict__ adjw) {
    int gid  = blockIdx.x * 4 + (threadIdx.x >> 6);
    int lane = threadIdx.x & 63;
    int w64  = gid & 15;
    int bn   = gid >> 4;
    int v = adj[(size_t)bn * N_ + w64 * 64 + lane];
    unsigned long long mask = __ballot(v != 0);
    if (lane == 0)  adjw[bn * 32 + w64 * 2]     = (unsigned)mask;
    if (lane == 32) adjw[bn * 32 + w64 * 2 + 1] = (unsigned)(mask >> 32);
}

// ---------------------------------------------------------------------------
__global__ __launch_bounds__(256) void build_x(const float* __restrict__ ents,
                                               const int* __restrict__ rels,
                                               const float* __restrict__ renc,
                                               bf16* __restrict__ x) {
    int idx  = blockIdx.x * 256 + threadIdx.x;
    int col8 = (idx & 63) * 8;
    int row  = idx >> 6;
    int b = row >> 10, n = row & 1023;
    const float* src;
    if (n < E_) src = ents + ((size_t)(b * E_ + n)) * HSZ_ + col8;
    else {
        int rt = rels[b * R_ + (n - E_)];
        src = renc + (size_t)rt * HSZ_ + col8;
    }
    float4 a = *(const float4*)src;
    float4 c = *(const float4*)(src + 4);
    bf16x8 v;
    v[0] = (bf16)a.x; v[1] = (bf16)a.y; v[2] = (bf16)a.z; v[3] = (bf16)a.w;
    v[4] = (bf16)c.x; v[5] = (bf16)c.y; v[6] = (bf16)c.z; v[7] = (bf16)c.w;
    *(bf16x8*)(x + (size_t)row * HSZ_ + col8) = v;
}

// ---------------------------------------------------------------------------
// GEMM, m97 structure: C(M x Nn) = A(M x Kk) @ Bt(Nn x Kk)^T, 128x128 tile,
// BK=64, 4 waves (2x2), 4x4 16x16x32 MFMA tiles/wave.
// R15 change: staging via global_load_lds width-16 into LINEAR (unpadded) LDS
// (the 517->874 TF step of the verified ladder). ds_read conflicts on the
// fragment loads are the m97-accepted cost.
template <int MODE>
__global__ __launch_bounds__(256) void gemm_bt(const bf16* __restrict__ A,
                                               const bf16* __restrict__ Bt,
                                               const float* __restrict__ biasF,
                                               const float* __restrict__ alphaF,
                                               const bf16* __restrict__ extraB,
                                               bf16* __restrict__ outB,
                                               float* __restrict__ outF,
                                               int Nn, int Kk) {
    __shared__ bf16 As[128][64];
    __shared__ bf16 Bs[128][64];
    int n0 = blockIdx.x * 128, m0 = blockIdx.y * 128;
    int t = threadIdx.x;
    int lane = t & 63, r = lane & 15, quad = lane >> 4;
    int w = t >> 6;
    int wm = w >> 1, wn = w & 1;
    f32x4 acc[4][4];
    #pragma unroll
    for (int mt = 0; mt < 4; mt++)
        #pragma unroll
        for (int nt = 0; nt < 4; nt++) acc[mt][nt] = (f32x4){0.f, 0.f, 0.f, 0.f};

    for (int k0 = 0; k0 < Kk; k0 += 64) {
        #pragma unroll
        for (int i = 0; i < 4; i++) {
            int e = i * 256 + t;              // 16B chunk index; 8 chunks/row
            int row = e >> 3, c8 = (e & 7) * 8;
            glds16(&A[(size_t)(m0 + row) * Kk + k0 + c8], &As[row][c8]);
            glds16(&Bt[(size_t)(n0 + row) * Kk + k0 + c8], &Bs[row][c8]);
        }
        __syncthreads();   // drains vmcnt (incl. global_load_lds) + barrier
        #pragma unroll
        for (int kk = 0; kk < 64; kk += 32) {
            bf16x8 af[4], bfr[4];
            #pragma unroll
            for (int mt = 0; mt < 4; mt++)
                af[mt] = *(const bf16x8*)&As[wm * 64 + mt * 16 + r][kk + quad * 8];
            #pragma unroll
            for (int nt = 0; nt < 4; nt++)
                bfr[nt] = *(const bf16x8*)&Bs[wn * 64 + nt * 16 + r][kk + quad * 8];
            #pragma unroll
            for (int mt = 0; mt < 4; mt++)
                #pragma unroll
                for (int nt = 0; nt < 4; nt++)
                    acc[mt][nt] = __builtin_amdgcn_mfma_f32_16x16x32_bf16(af[mt], bfr[nt], acc[mt][nt], 0, 0, 0);
        }
        __syncthreads();
    }
    #pragma unroll
    for (int mt = 0; mt < 4; mt++) {
        #pragma unroll
        for (int nt = 0; nt < 4; nt++) {
            #pragma unroll
            for (int i = 0; i < 4; i++) {
                int rg = m0 + wm * 64 + mt * 16 + quad * 4 + i;
                int cg = n0 + wn * 64 + nt * 16 + r;
                float v = acc[mt][nt][i];
                if (MODE == 0) {
                    outB[(size_t)rg * Nn + cg] = (bf16)v;
                } else if (MODE == 1) {
                    int bb = rg >> 10, n = rg & 1023;
                    outB[(size_t)(bb * HSZ_ + cg) * N_ + n] = (bf16)v;
                } else if (MODE == 2) {
                    v += biasF[cg];
                    float a = alphaF[cg];
                    v = v > 0.f ? v : a * v;
                    outB[(size_t)rg * Nn + cg] = (bf16)v;
                } else {
                    v += biasF[cg] + (float)extraB[(size_t)rg * Nn + cg];
                    outF[(size_t)rg * Nn + cg] = v;
                }
            }
        }
    }
}

// ---------------------------------------------------------------------------
// Fused MFMA attention v8. R15 changes vs v7 (which was latency-bound:
// MfmaUtil 9.3 / VALUBusy 17.5 / HBM 6.2 / Occ 22.7 -- nothing busy, and
// LDS 44.5KB -> 3 blk/CU -> 256-block tail at 1 blk/CU):
//  - V is NOT staged: PV reads Vt fragments direct from L2 (256KB/head,
//    shared by the 16 XCD-colocated q-blocks; guide mistake #7 -- staging
//    L2-fit data is pure overhead). LDS 44544 -> 26112 B -> 6 blk/CU,
//    whole 1024-block grid co-resident, no tail.
//  - plds barrier removed: plds[w] is strictly per-wave; same-wave DS
//    write->read is ordered (in-order LDS pipe + compiler lgkmcnt).
//  - launch_bounds(256,4): cap VGPR<=128 so >=4 blk/CU is guaranteed.
// Proven-kept: padded Ks[64][136], plds[4][16][68], XCD-swizzled grid,
// fixed-shift masked softmax.
__global__ __launch_bounds__(256, 4) void attn_fused(const bf16* __restrict__ Q,
                                                     const bf16* __restrict__ K,
                                                     const bf16* __restrict__ Vt,
                                                     const unsigned* __restrict__ adjw,
                                                     const bf16* __restrict__ xb,
                                                     float* __restrict__ tpre) {
    int blk = blockIdx.x;
    // blk = gr + 8*(qb + 16*gq): group g = gq*8+gr = b*4+h -> all 16 q-blocks
    // of a group share blk%8 (same XCD on round-robin dispatch).
    int gr = blk & 7;
    int qb = (blk >> 3) & 15;
    int gq = blk >> 7;
    int g = gq * 8 + gr;
    int b = g >> 2, h = g & 3;

    int tid = threadIdx.x;
    int w = tid >> 6, lane = tid & 63;
    int r = lane & 15, quad = lane >> 4;
    int n0 = qb * 64 + w * 16;       // this wave's 16 q-rows

    __shared__ bf16 Ks[64][136];     // [key][dim], +8 pad (proven layout)
    __shared__ bf16 plds[4][16][68]; // per-wave P tile, padded

    bf16x8 qf[4];
    const bf16* qbase = Q + ((size_t)(b * N_ + n0 + r)) * HSZ_ + h * 128;
    #pragma unroll
    for (int kc = 0; kc < 4; kc++) qf[kc] = *(const bf16x8*)(qbase + kc * 32 + quad * 8);

    f32x4 accv[8];
    #pragma unroll
    for (int dt = 0; dt < 8; dt++) accv[dt] = (f32x4){0.f, 0.f, 0.f, 0.f};
    float tl[4] = {0.f, 0.f, 0.f, 0.f};
    const float scale = 0.04419417382415922f;   // 1/sqrt(512)
    const float SHIFT = 12.0f;

    for (int it = 0; it < 16; it++) {
        int key0 = it * 64;
        __syncthreads();   // all waves done reading Ks from prev iter
        // stage K tile 64x128: 1024 uint4, 4/thread
        #pragma unroll
        for (int i = 0; i < 4; i++) {
            int e = tid + i * 256;
            int krow = e >> 4, kc8 = (e & 15) * 8;
            *(uint4*)&Ks[krow][kc8] =
                *(const uint4*)&K[((size_t)(b * N_ + key0 + krow)) * HSZ_ + h * 128 + kc8];
        }
        __syncthreads();   // staging visible

        // QK^T: 4 groups of 16 keys from LDS
        f32x4 cg[4];
        #pragma unroll
        for (int gk = 0; gk < 4; gk++) cg[gk] = (f32x4){0.f, 0.f, 0.f, 0.f};
        #pragma unroll
        for (int gk = 0; gk < 4; gk++)
            #pragma unroll
            for (int kc = 0; kc < 4; kc++) {
                bf16x8 kf = *(const bf16x8*)&Ks[gk * 16 + r][kc * 32 + quad * 8];
                cg[gk] = __builtin_amdgcn_mfma_f32_16x16x32_bf16(qf[kc], kf, cg[gk], 0, 0, 0);
            }
        // mask + exp -> plds + tl
        #pragma unroll
        for (int i = 0; i < 4; i++) {
            int row_g = n0 + quad * 4 + i;
            const unsigned* aw = &adjw[((size_t)(b << 10) + row_g) * 32 + it * 2];
            unsigned wb0 = aw[0], wb1 = aw[1];
            float p0 = ((wb0 >> r) & 1u)        ? __expf(cg[0][i] * scale - SHIFT) : 0.f;
            float p1 = ((wb0 >> (16 + r)) & 1u) ? __expf(cg[1][i] * scale - SHIFT) : 0.f;
            float p2 = ((wb1 >> r) & 1u)        ? __expf(cg[2][i] * scale - SHIFT) : 0.f;
            float p3 = ((wb1 >> (16 + r)) & 1u) ? __expf(cg[3][i] * scale - SHIFT) : 0.f;
            tl[i] += p0 + p1 + p2 + p3;
            plds[w][quad * 4 + i][r]      = (bf16)p0;
            plds[w][quad * 4 + i][16 + r] = (bf16)p1;
            plds[w][quad * 4 + i][32 + r] = (bf16)p2;
            plds[w][quad * 4 + i][48 + r] = (bf16)p3;
        }
        // no barrier: plds[w] is wave-private; same-wave DS ordering suffices

        // PV: P (A-op, 64 keys in 2 k-chunks) x V direct from global/L2
        bf16x8 pf0 = *(const bf16x8*)&plds[w][r][quad * 8];
        bf16x8 pf1 = *(const bf16x8*)&plds[w][r][32 + quad * 8];
        #pragma unroll
        for (int dt = 0; dt < 8; dt++) {
            const bf16* vp = Vt + ((size_t)(b * HSZ_ + h * 128 + dt * 16 + r)) * N_
                           + key0 + quad * 8;
            bf16x8 v0 = *(const bf16x8*)vp;
            bf16x8 v1 = *(const bf16x8*)(vp + 32);
            accv[dt] = __builtin_amdgcn_mfma_f32_16x16x32_bf16(pf0, v0, accv[dt], 0, 0, 0);
            accv[dt] = __builtin_amdgcn_mfma_f32_16x16x32_bf16(pf1, v1, accv[dt], 0, 0, 0);
        }
    }
    // per-wave epilogue
    #pragma unroll
    for (int i = 0; i < 4; i++) {
        float l = tl[i];
        #pragma unroll
        for (int d = 1; d < 16; d <<= 1) l += __shfl_xor(l, d, 64);
        float inv_l = 1.0f / fmaxf(l, 1e-30f);
        #pragma unroll
        for (int dt = 0; dt < 8; dt++) {
            int row = n0 + quad * 4 + i;
            int col = h * 128 + dt * 16 + r;
            size_t idx = ((size_t)(b * N_ + row)) * HSZ_ + col;
            tpre[idx] = accv[dt][i] * inv_l + (float)xb[idx];
        }
    }
}

// ---------------------------------------------------------------------------
__global__ __launch_bounds__(64) void lnorm_k(const float* __restrict__ in,
                                              const float* __restrict__ sc,
                                              const float* __restrict__ bi,
                                              bf16* __restrict__ out) {
    int row = blockIdx.x;
    int lane = threadIdx.x;
    const float* rp = in + (size_t)row * HSZ_;
    float4 a = *(const float4*)(rp + lane * 4);
    float4 b = *(const float4*)(rp + 256 + lane * 4);
    float sum = a.x + a.y + a.z + a.w + b.x + b.y + b.z + b.w;
    float sq  = a.x*a.x + a.y*a.y + a.z*a.z + a.w*a.w
              + b.x*b.x + b.y*b.y + b.z*b.z + b.w*b.w;
    #pragma unroll
    for (int d = 1; d < 64; d <<= 1) {
        sum += __shfl_xor(sum, d, 64);
        sq  += __shfl_xor(sq,  d, 64);
    }
    float mu = sum * (1.0f / HSZ_);
    float varv = fmaxf(sq * (1.0f / HSZ_) - mu * mu, 0.f);
    float rs = rsqrtf(varv + 1e-5f);
    bf16* op = out + (size_t)row * HSZ_;
    int c0 = lane * 4;
    float va[4] = {a.x, a.y, a.z, a.w}, vb[4] = {b.x, b.y, b.z, b.w};
    #pragma unroll
    for (int k = 0; k < 4; k++) {
        op[c0 + k]       = (bf16)(((va[k] - mu) * rs) * sc[c0 + k] + bi[c0 + k]);
        op[c0 + 256 + k] = (bf16)(((vb[k] - mu) * rs) * sc[c0 + 256 + k] + bi[c0 + 256 + k]);
    }
}

// ---------------------------------------------------------------------------
__global__ __launch_bounds__(256) void write_out(const bf16* __restrict__ x,
                                                 float* __restrict__ out) {
    size_t tid = (size_t)blockIdx.x * 256 + threadIdx.x;
    if (tid < (size_t)B_ * HSZ_) {
        int b = (int)(tid >> 9), c = (int)(tid & 511);
        out[tid] = (float)x[((size_t)(b * N_ + E_)) * HSZ_ + c];
    } else if (tid < (size_t)B_ * HSZ_ + (size_t)B_ * N_ * HSZ_) {
        out[tid] = (float)x[tid - B_ * HSZ_];
    } else {
        out[tid] = 1.0f;
    }
}

// ---------------------------------------------------------------------------
extern "C" void kernel_launch(void* const* d_in, const int* in_sizes, int n_in,
                              void* d_out, int out_size, void* d_ws, size_t ws_size,
                              hipStream_t stream) {
    const float* ents = (const float*)d_in[0];
    const int*   rels = (const int*)d_in[1];
    const int*   adj  = (const int*)d_in[2];
    const float* renc = (const float*)d_in[3];
    const float* Wq   = (const float*)d_in[4];
    const float* Wk   = (const float*)d_in[5];
    const float* Wv   = (const float*)d_in[6];
    const float* l1w  = (const float*)d_in[7];
    const float* l1b  = (const float*)d_in[8];
    const float* l2w  = (const float*)d_in[9];
    const float* l2b  = (const float*)d_in[10];
    const float* ln1s = (const float*)d_in[11];
    const float* ln1b = (const float*)d_in[12];
    const float* ln2s = (const float*)d_in[13];
    const float* ln2b = (const float*)d_in[14];
    const float* pa   = (const float*)d_in[15];

    char* ws = (char*)d_ws;
    size_t o = 0;
    auto alloc = [&](size_t bytes) { void* p = ws + o; o += bytes; return p; };
    bf16*     WqT    = (bf16*)alloc(1048576);
    bf16*     WkT    = (bf16*)alloc(1048576);
    bf16*     WvT    = (bf16*)alloc(1048576);
    bf16*     L1T    = (bf16*)alloc(4194304);
    bf16*     L2T    = (bf16*)alloc(4194304);
    unsigned* adjw   = (unsigned*)alloc(2097152);
    bf16*     xb     = (bf16*)alloc(16777216);
    bf16*     Qb     = (bf16*)alloc(16777216);
    bf16*     Kb     = (bf16*)alloc(16777216);
    bf16*     Vt     = (bf16*)alloc(16777216);
    bf16*     tb     = (bf16*)alloc(16777216);
    bf16*     hb     = (bf16*)alloc(67108864);
    float*    f32buf = (float*)alloc(33554432);
    if (o > ws_size) return;

    dim3 t32(32, 8);
    for (int j = 0; j < 2; j++) {
        transpose_f32_bf16<<<dim3(16, 16), t32, 0, stream>>>(Wq  + j * 262144,  WqT + j * 262144, 512, 512);
        transpose_f32_bf16<<<dim3(16, 16), t32, 0, stream>>>(Wk  + j * 262144,  WkT + j * 262144, 512, 512);
        transpose_f32_bf16<<<dim3(16, 16), t32, 0, stream>>>(Wv  + j * 262144,  WvT + j * 262144, 512, 512);
        transpose_f32_bf16<<<dim3(64, 16), t32, 0, stream>>>(l1w + j * 1048576, L1T + j * 1048576, 512, 2048);
        transpose_f32_bf16<<<dim3(16, 64), t32, 0, stream>>>(l2w + j * 1048576, L2T + j * 1048576, 2048, 512);
    }
    pack_adj<<<65536, 256, 0, stream>>>(adj, adjw);
    build_x<<<4096, 256, 0, stream>>>(ents, rels, renc, xb);

    for (int j = 0; j < 2; j++) {
        gemm_bt<0><<<dim3(4, 128), 256, 0, stream>>>(xb, WqT + j * 262144, nullptr, nullptr, nullptr, Qb, nullptr, 512, 512);
        gemm_bt<0><<<dim3(4, 128), 256, 0, stream>>>(xb, WkT + j * 262144, nullptr, nullptr, nullptr, Kb, nullptr, 512, 512);
        gemm_bt<1><<<dim3(4, 128), 256, 0, stream>>>(xb, WvT + j * 262144, nullptr, nullptr, nullptr, Vt, nullptr, 512, 512);
        attn_fused<<<1024, 256, 0, stream>>>(Qb, Kb, Vt, adjw, xb, f32buf);
        lnorm_k<<<16384, 64, 0, stream>>>(f32buf, ln1s + j * 512, ln1b + j * 512, tb);
        gemm_bt<2><<<dim3(16, 128), 256, 0, stream>>>(tb, L1T + j * 1048576, l1b + j * 2048, pa + j * 2048, nullptr, hb, nullptr, 2048, 512);
        gemm_bt<3><<<dim3(4, 128), 256, 0, stream>>>(hb, L2T + j * 1048576, l2b + j * 512, nullptr, tb, nullptr, f32buf, 512, 2048);
        lnorm_k<<<16384, 64, 0, stream>>>(f32buf, ln2s + j * 512, ln2b + j * 512, xb);
    }
    write_out<<<32864, 256, 0, stream>>>(xb, (float*)d_out);
}

// Round 3
// 769.924 us; speedup vs baseline: 1.1511x; 1.1511x over previous
//
#include <hip/hip_runtime.h>
#include <hip/hip_bf16.h>

typedef __bf16 bf16;
typedef __attribute__((ext_vector_type(8))) bf16 bf16x8;
typedef __attribute__((ext_vector_type(4))) float f32x4;

constexpr int B_   = 16;
constexpr int E_   = 400;
constexpr int R_   = 624;
constexpr int N_   = 1024;
constexpr int HSZ_ = 512;
constexpr int DFF_ = 2048;
constexpr int M_   = B_ * N_;

// global -> LDS direct DMA, 16B per lane (wave-uniform base + lane*16 dest).
__device__ __forceinline__ void glds16(const void* g, void* l) {
    __builtin_amdgcn_global_load_lds((const __attribute__((address_space(1))) void*)g,
                                     (__attribute__((address_space(3))) void*)l,
                                     16, 0, 0);
}

// ---------------------------------------------------------------------------
__global__ __launch_bounds__(256) void transpose_f32_bf16(const float* __restrict__ in,
                                                          bf16* __restrict__ out,
                                                          int rows, int cols) {
    __shared__ float tile[32][33];
    int c0 = blockIdx.x * 32, r0 = blockIdx.y * 32;
    int tx = threadIdx.x, ty = threadIdx.y;   // 32 x 8
    #pragma unroll
    for (int i = 0; i < 32; i += 8)
        tile[ty + i][tx] = in[(size_t)(r0 + ty + i) * cols + (c0 + tx)];
    __syncthreads();
    #pragma unroll
    for (int i = 0; i < 32; i += 8)
        out[(size_t)(c0 + ty + i) * rows + (r0 + tx)] = (bf16)tile[tx][ty + i];
}

// ---------------------------------------------------------------------------
__global__ __launch_bounds__(256) void pack_adj(const int* __restrict__ adj,
                                                unsigned* __restrict__ adjw) {
    int gid  = blockIdx.x * 4 + (threadIdx.x >> 6);
    int lane = threadIdx.x & 63;
    int w64  = gid & 15;
    int bn   = gid >> 4;
    int v = adj[(size_t)bn * N_ + w64 * 64 + lane];
    unsigned long long mask = __ballot(v != 0);
    if (lane == 0)  adjw[bn * 32 + w64 * 2]     = (unsigned)mask;
    if (lane == 32) adjw[bn * 32 + w64 * 2 + 1] = (unsigned)(mask >> 32);
}

// ---------------------------------------------------------------------------
__global__ __launch_bounds__(256) void build_x(const float* __restrict__ ents,
                                               const int* __restrict__ rels,
                                               const float* __restrict__ renc,
                                               bf16* __restrict__ x) {
    int idx  = blockIdx.x * 256 + threadIdx.x;
    int col8 = (idx & 63) * 8;
    int row  = idx >> 6;
    int b = row >> 10, n = row & 1023;
    const float* src;
    if (n < E_) src = ents + ((size_t)(b * E_ + n)) * HSZ_ + col8;
    else {
        int rt = rels[b * R_ + (n - E_)];
        src = renc + (size_t)rt * HSZ_ + col8;
    }
    float4 a = *(const float4*)src;
    float4 c = *(const float4*)(src + 4);
    bf16x8 v;
    v[0] = (bf16)a.x; v[1] = (bf16)a.y; v[2] = (bf16)a.z; v[3] = (bf16)a.w;
    v[4] = (bf16)c.x; v[5] = (bf16)c.y; v[6] = (bf16)c.z; v[7] = (bf16)c.w;
    *(bf16x8*)(x + (size_t)row * HSZ_ + col8) = v;
}

// ---------------------------------------------------------------------------
// GEMM, m97 structure: C(M x Nn) = A(M x Kk) @ Bt(Nn x Kk)^T, 128x128 tile,
// BK=64, 4 waves (2x2), 4x4 16x16x32 MFMA tiles/wave, glds16 linear staging.
// MODE 4 (R16): fused QKV — Nn=1536, cols 0-511 -> outB (Qb row-major),
// 512-1023 -> outB2 (Kb row-major), 1024-1535 -> outB3 (Vt transposed).
// Branch is block-uniform (128-col tile never crosses a 512 boundary).
template <int MODE>
__global__ __launch_bounds__(256) void gemm_bt(const bf16* __restrict__ A,
                                               const bf16* __restrict__ Bt,
                                               const float* __restrict__ biasF,
                                               const float* __restrict__ alphaF,
                                               const bf16* __restrict__ extraB,
                                               bf16* __restrict__ outB,
                                               bf16* __restrict__ outB2,
                                               bf16* __restrict__ outB3,
                                               float* __restrict__ outF,
                                               int Nn, int Kk) {
    __shared__ bf16 As[128][64];
    __shared__ bf16 Bs[128][64];
    int n0 = blockIdx.x * 128, m0 = blockIdx.y * 128;
    int t = threadIdx.x;
    int lane = t & 63, r = lane & 15, quad = lane >> 4;
    int w = t >> 6;
    int wm = w >> 1, wn = w & 1;
    f32x4 acc[4][4];
    #pragma unroll
    for (int mt = 0; mt < 4; mt++)
        #pragma unroll
        for (int nt = 0; nt < 4; nt++) acc[mt][nt] = (f32x4){0.f, 0.f, 0.f, 0.f};

    for (int k0 = 0; k0 < Kk; k0 += 64) {
        #pragma unroll
        for (int i = 0; i < 4; i++) {
            int e = i * 256 + t;              // 16B chunk index; 8 chunks/row
            int row = e >> 3, c8 = (e & 7) * 8;
            glds16(&A[(size_t)(m0 + row) * Kk + k0 + c8], &As[row][c8]);
            glds16(&Bt[(size_t)(n0 + row) * Kk + k0 + c8], &Bs[row][c8]);
        }
        __syncthreads();   // drains vmcnt (incl. global_load_lds) + barrier
        #pragma unroll
        for (int kk = 0; kk < 64; kk += 32) {
            bf16x8 af[4], bfr[4];
            #pragma unroll
            for (int mt = 0; mt < 4; mt++)
                af[mt] = *(const bf16x8*)&As[wm * 64 + mt * 16 + r][kk + quad * 8];
            #pragma unroll
            for (int nt = 0; nt < 4; nt++)
                bfr[nt] = *(const bf16x8*)&Bs[wn * 64 + nt * 16 + r][kk + quad * 8];
            #pragma unroll
            for (int mt = 0; mt < 4; mt++)
                #pragma unroll
                for (int nt = 0; nt < 4; nt++)
                    acc[mt][nt] = __builtin_amdgcn_mfma_f32_16x16x32_bf16(af[mt], bfr[nt], acc[mt][nt], 0, 0, 0);
        }
        __syncthreads();
    }
    #pragma unroll
    for (int mt = 0; mt < 4; mt++) {
        #pragma unroll
        for (int nt = 0; nt < 4; nt++) {
            #pragma unroll
            for (int i = 0; i < 4; i++) {
                int rg = m0 + wm * 64 + mt * 16 + quad * 4 + i;
                int cg = n0 + wn * 64 + nt * 16 + r;
                float v = acc[mt][nt][i];
                if (MODE == 0) {
                    outB[(size_t)rg * Nn + cg] = (bf16)v;
                } else if (MODE == 1) {
                    int bb = rg >> 10, n = rg & 1023;
                    outB[(size_t)(bb * HSZ_ + cg) * N_ + n] = (bf16)v;
                } else if (MODE == 2) {
                    v += biasF[cg];
                    float a = alphaF[cg];
                    v = v > 0.f ? v : a * v;
                    outB[(size_t)rg * Nn + cg] = (bf16)v;
                } else if (MODE == 3) {
                    v += biasF[cg] + (float)extraB[(size_t)rg * Nn + cg];
                    outF[(size_t)rg * Nn + cg] = v;
                } else {   // MODE 4: fused QKV
                    if (cg < 512) {
                        outB[(size_t)rg * HSZ_ + cg] = (bf16)v;
                    } else if (cg < 1024) {
                        outB2[(size_t)rg * HSZ_ + (cg - 512)] = (bf16)v;
                    } else {
                        int bb = rg >> 10, n = rg & 1023;
                        outB3[(size_t)(bb * HSZ_ + (cg - 1024)) * N_ + n] = (bf16)v;
                    }
                }
            }
        }
    }
}

// ---------------------------------------------------------------------------
// Fused MFMA attention v9. Post-mortems:
//  - v7 (144us): 3 blk/CU + 256-block tail; 3 barriers/iter; MfmaUtil 9.3.
//  - v8 (162us): direct-L2 V REGRESSED (+18us) despite 44% occupancy --
//    kernel is per-wave latency-bound, not occupancy-bound. Staged V is back.
// v9 lever: 2x work per staged byte / per barrier. 128 q-rows per block
// (wave owns 32 rows = 2 m-tiles), grid 1024 -> 512 (2/CU, fully resident,
// zero tail). Same staging + 2 barriers now feed 64 MFMA/wave/iter (was 32),
// K-fragments shared across m-tiles (16 ds_reads : 32 MFMA), per-CU barrier
// count halved. plds barrier-free (v8-proven). Proven layouts kept.
__global__ __launch_bounds__(256) void attn_fused(const bf16* __restrict__ Q,
                                                  const bf16* __restrict__ K,
                                                  const bf16* __restrict__ Vt,
                                                  const unsigned* __restrict__ adjw,
                                                  const bf16* __restrict__ xb,
                                                  float* __restrict__ tpre) {
    int blk = blockIdx.x;
    // blk = gr + 8*(qb + 8*gq): group g = gq*8+gr = b*4+h -> the 8 q-blocks
    // of a group share blk%8 (same XCD on round-robin dispatch).
    int gr = blk & 7;
    int qb = (blk >> 3) & 7;
    int gq = blk >> 6;
    int g = gq * 8 + gr;
    int b = g >> 2, h = g & 3;

    int tid = threadIdx.x;
    int w = tid >> 6, lane = tid & 63;
    int r = lane & 15, quad = lane >> 4;
    int n0 = qb * 128 + w * 32;      // this wave's 32 q-rows (2 m-tiles)

    __shared__ bf16 Ks[64][136];     // [key][dim], +8 pad -> 2-way (free)
    __shared__ bf16 Vs[128][72];     // [dim][key], +8 pad -> 2-way (free)
    __shared__ bf16 plds[4][32][68]; // per-wave P tile, padded

    bf16x8 qf[2][4];
    #pragma unroll
    for (int mt = 0; mt < 2; mt++) {
        const bf16* qbase = Q + ((size_t)(b * N_ + n0 + mt * 16 + r)) * HSZ_ + h * 128;
        #pragma unroll
        for (int kc = 0; kc < 4; kc++) qf[mt][kc] = *(const bf16x8*)(qbase + kc * 32 + quad * 8);
    }

    f32x4 accv[2][8];
    #pragma unroll
    for (int mt = 0; mt < 2; mt++)
        #pragma unroll
        for (int dt = 0; dt < 8; dt++) accv[mt][dt] = (f32x4){0.f, 0.f, 0.f, 0.f};
    float tl[2][4] = {{0.f, 0.f, 0.f, 0.f}, {0.f, 0.f, 0.f, 0.f}};
    const float scale = 0.04419417382415922f;   // 1/sqrt(512)
    const float SHIFT = 12.0f;

    for (int it = 0; it < 16; it++) {
        int key0 = it * 64;
        __syncthreads();   // all waves done reading Ks/Vs from prev iter
        // stage K tile 64x128: 1024 uint4, 4/thread
        #pragma unroll
        for (int i = 0; i < 4; i++) {
            int e = tid + i * 256;
            int krow = e >> 4, kc8 = (e & 15) * 8;
            *(uint4*)&Ks[krow][kc8] =
                *(const uint4*)&K[((size_t)(b * N_ + key0 + krow)) * HSZ_ + h * 128 + kc8];
        }
        // stage V tile 128x64: 1024 uint4, 4/thread
        #pragma unroll
        for (int i = 0; i < 4; i++) {
            int e = tid + i * 256;
            int vrow = e >> 3, vc8 = (e & 7) * 8;
            *(uint4*)&Vs[vrow][vc8] =
                *(const uint4*)&Vt[((size_t)(b * HSZ_ + h * 128 + vrow)) * N_ + key0 + vc8];
        }
        __syncthreads();   // staging visible

        // QK^T: 4 groups of 16 keys; K-fragment shared by both m-tiles
        f32x4 cg[2][4];
        #pragma unroll
        for (int mt = 0; mt < 2; mt++)
            #pragma unroll
            for (int gk = 0; gk < 4; gk++) cg[mt][gk] = (f32x4){0.f, 0.f, 0.f, 0.f};
        #pragma unroll
        for (int gk = 0; gk < 4; gk++)
            #pragma unroll
            for (int kc = 0; kc < 4; kc++) {
                bf16x8 kf = *(const bf16x8*)&Ks[gk * 16 + r][kc * 32 + quad * 8];
                cg[0][gk] = __builtin_amdgcn_mfma_f32_16x16x32_bf16(qf[0][kc], kf, cg[0][gk], 0, 0, 0);
                cg[1][gk] = __builtin_amdgcn_mfma_f32_16x16x32_bf16(qf[1][kc], kf, cg[1][gk], 0, 0, 0);
            }
        // mask + exp -> plds + tl
        #pragma unroll
        for (int mt = 0; mt < 2; mt++)
            #pragma unroll
            for (int i = 0; i < 4; i++) {
                int row_l = mt * 16 + quad * 4 + i;
                int row_g = n0 + row_l;
                const unsigned* aw = &adjw[((size_t)(b << 10) + row_g) * 32 + it * 2];
                unsigned wb0 = aw[0], wb1 = aw[1];
                float p0 = ((wb0 >> r) & 1u)        ? __expf(cg[mt][0][i] * scale - SHIFT) : 0.f;
                float p1 = ((wb0 >> (16 + r)) & 1u) ? __expf(cg[mt][1][i] * scale - SHIFT) : 0.f;
                float p2 = ((wb1 >> r) & 1u)        ? __expf(cg[mt][2][i] * scale - SHIFT) : 0.f;
                float p3 = ((wb1 >> (16 + r)) & 1u) ? __expf(cg[mt][3][i] * scale - SHIFT) : 0.f;
                tl[mt][i] += p0 + p1 + p2 + p3;
                plds[w][row_l][r]      = (bf16)p0;
                plds[w][row_l][16 + r] = (bf16)p1;
                plds[w][row_l][32 + r] = (bf16)p2;
                plds[w][row_l][48 + r] = (bf16)p3;
            }
        // no barrier: plds[w] is wave-private; same-wave DS ordering suffices

        // PV: P (A-op, 64 keys in 2 k-chunks) x Vs; V-fragments shared by m-tiles
        bf16x8 pf00 = *(const bf16x8*)&plds[w][r][quad * 8];
        bf16x8 pf01 = *(const bf16x8*)&plds[w][r][32 + quad * 8];
        bf16x8 pf10 = *(const bf16x8*)&plds[w][16 + r][quad * 8];
        bf16x8 pf11 = *(const bf16x8*)&plds[w][16 + r][32 + quad * 8];
        #pragma unroll
        for (int dt = 0; dt < 8; dt++) {
            bf16x8 v0 = *(const bf16x8*)&Vs[dt * 16 + r][quad * 8];
            bf16x8 v1 = *(const bf16x8*)&Vs[dt * 16 + r][32 + quad * 8];
            accv[0][dt] = __builtin_amdgcn_mfma_f32_16x16x32_bf16(pf00, v0, accv[0][dt], 0, 0, 0);
            accv[0][dt] = __builtin_amdgcn_mfma_f32_16x16x32_bf16(pf01, v1, accv[0][dt], 0, 0, 0);
            accv[1][dt] = __builtin_amdgcn_mfma_f32_16x16x32_bf16(pf10, v0, accv[1][dt], 0, 0, 0);
            accv[1][dt] = __builtin_amdgcn_mfma_f32_16x16x32_bf16(pf11, v1, accv[1][dt], 0, 0, 0);
        }
    }
    // per-wave epilogue
    #pragma unroll
    for (int mt = 0; mt < 2; mt++)
        #pragma unroll
        for (int i = 0; i < 4; i++) {
            float l = tl[mt][i];
            #pragma unroll
            for (int d = 1; d < 16; d <<= 1) l += __shfl_xor(l, d, 64);
            float inv_l = 1.0f / fmaxf(l, 1e-30f);
            #pragma unroll
            for (int dt = 0; dt < 8; dt++) {
                int row = n0 + mt * 16 + quad * 4 + i;
                int col = h * 128 + dt * 16 + r;
                size_t idx = ((size_t)(b * N_ + row)) * HSZ_ + col;
                tpre[idx] = accv[mt][dt][i] * inv_l + (float)xb[idx];
            }
        }
}

// ---------------------------------------------------------------------------
__global__ __launch_bounds__(64) void lnorm_k(const float* __restrict__ in,
                                              const float* __restrict__ sc,
                                              const float* __restrict__ bi,
                                              bf16* __restrict__ out) {
    int row = blockIdx.x;
    int lane = threadIdx.x;
    const float* rp = in + (size_t)row * HSZ_;
    float4 a = *(const float4*)(rp + lane * 4);
    float4 b = *(const float4*)(rp + 256 + lane * 4);
    float sum = a.x + a.y + a.z + a.w + b.x + b.y + b.z + b.w;
    float sq  = a.x*a.x + a.y*a.y + a.z*a.z + a.w*a.w
              + b.x*b.x + b.y*b.y + b.z*b.z + b.w*b.w;
    #pragma unroll
    for (int d = 1; d < 64; d <<= 1) {
        sum += __shfl_xor(sum, d, 64);
        sq  += __shfl_xor(sq,  d, 64);
    }
    float mu = sum * (1.0f / HSZ_);
    float varv = fmaxf(sq * (1.0f / HSZ_) - mu * mu, 0.f);
    float rs = rsqrtf(varv + 1e-5f);
    bf16* op = out + (size_t)row * HSZ_;
    int c0 = lane * 4;
    float va[4] = {a.x, a.y, a.z, a.w}, vb[4] = {b.x, b.y, b.z, b.w};
    #pragma unroll
    for (int k = 0; k < 4; k++) {
        op[c0 + k]       = (bf16)(((va[k] - mu) * rs) * sc[c0 + k] + bi[c0 + k]);
        op[c0 + 256 + k] = (bf16)(((vb[k] - mu) * rs) * sc[c0 + 256 + k] + bi[c0 + 256 + k]);
    }
}

// ---------------------------------------------------------------------------
__global__ __launch_bounds__(256) void write_out(const bf16* __restrict__ x,
                                                 float* __restrict__ out) {
    size_t tid = (size_t)blockIdx.x * 256 + threadIdx.x;
    if (tid < (size_t)B_ * HSZ_) {
        int b = (int)(tid >> 9), c = (int)(tid & 511);
        out[tid] = (float)x[((size_t)(b * N_ + E_)) * HSZ_ + c];
    } else if (tid < (size_t)B_ * HSZ_ + (size_t)B_ * N_ * HSZ_) {
        out[tid] = (float)x[tid - B_ * HSZ_];
    } else {
        out[tid] = 1.0f;
    }
}

// ---------------------------------------------------------------------------
extern "C" void kernel_launch(void* const* d_in, const int* in_sizes, int n_in,
                              void* d_out, int out_size, void* d_ws, size_t ws_size,
                              hipStream_t stream) {
    const float* ents = (const float*)d_in[0];
    const int*   rels = (const int*)d_in[1];
    const int*   adj  = (const int*)d_in[2];
    const float* renc = (const float*)d_in[3];
    const float* Wq   = (const float*)d_in[4];
    const float* Wk   = (const float*)d_in[5];
    const float* Wv   = (const float*)d_in[6];
    const float* l1w  = (const float*)d_in[7];
    const float* l1b  = (const float*)d_in[8];
    const float* l2w  = (const float*)d_in[9];
    const float* l2b  = (const float*)d_in[10];
    const float* ln1s = (const float*)d_in[11];
    const float* ln1b = (const float*)d_in[12];
    const float* ln2s = (const float*)d_in[13];
    const float* ln2b = (const float*)d_in[14];
    const float* pa   = (const float*)d_in[15];

    char* ws = (char*)d_ws;
    size_t o = 0;
    auto alloc = [&](size_t bytes) { void* p = ws + o; o += bytes; return p; };
    bf16*     WqkvT  = (bf16*)alloc(3145728);   // per j: 1536 rows x 512 (Wq|Wk|Wv)^T
    bf16*     L1T    = (bf16*)alloc(4194304);
    bf16*     L2T    = (bf16*)alloc(4194304);
    unsigned* adjw   = (unsigned*)alloc(2097152);
    bf16*     xb     = (bf16*)alloc(16777216);
    bf16*     Qb     = (bf16*)alloc(16777216);
    bf16*     Kb     = (bf16*)alloc(16777216);
    bf16*     Vt     = (bf16*)alloc(16777216);
    bf16*     tb     = (bf16*)alloc(16777216);
    bf16*     hb     = (bf16*)alloc(67108864);
    float*    f32buf = (float*)alloc(33554432);
    if (o > ws_size) return;

    dim3 t32(32, 8);
    for (int j = 0; j < 2; j++) {
        transpose_f32_bf16<<<dim3(16, 16), t32, 0, stream>>>(Wq  + j * 262144,  WqkvT + j * 786432,          512, 512);
        transpose_f32_bf16<<<dim3(16, 16), t32, 0, stream>>>(Wk  + j * 262144,  WqkvT + j * 786432 + 262144, 512, 512);
        transpose_f32_bf16<<<dim3(16, 16), t32, 0, stream>>>(Wv  + j * 262144,  WqkvT + j * 786432 + 524288, 512, 512);
        transpose_f32_bf16<<<dim3(64, 16), t32, 0, stream>>>(l1w + j * 1048576, L1T + j * 1048576, 512, 2048);
        transpose_f32_bf16<<<dim3(16, 64), t32, 0, stream>>>(l2w + j * 1048576, L2T + j * 1048576, 2048, 512);
    }
    pack_adj<<<65536, 256, 0, stream>>>(adj, adjw);
    build_x<<<4096, 256, 0, stream>>>(ents, rels, renc, xb);

    for (int j = 0; j < 2; j++) {
        gemm_bt<4><<<dim3(12, 128), 256, 0, stream>>>(xb, WqkvT + j * 786432, nullptr, nullptr, nullptr,
                                                      Qb, Kb, Vt, nullptr, 1536, 512);
        attn_fused<<<512, 256, 0, stream>>>(Qb, Kb, Vt, adjw, xb, f32buf);
        lnorm_k<<<16384, 64, 0, stream>>>(f32buf, ln1s + j * 512, ln1b + j * 512, tb);
        gemm_bt<2><<<dim3(16, 128), 256, 0, stream>>>(tb, L1T + j * 1048576, l1b + j * 2048, pa + j * 2048,
                                                      nullptr, hb, nullptr, nullptr, nullptr, 2048, 512);
        gemm_bt<3><<<dim3(4, 128), 256, 0, stream>>>(hb, L2T + j * 1048576, l2b + j * 512, nullptr,
                                                     tb, nullptr, nullptr, nullptr, f32buf, 512, 2048);
        lnorm_k<<<16384, 64, 0, stream>>>(f32buf, ln2s + j * 512, ln2b + j * 512, xb);
    }
    write_out<<<32864, 256, 0, stream>>>(xb, (float*)d_out);
}